// Round 4
// baseline (266.751 us; speedup 1.0000x reference)
//
#include <hip/hip_runtime.h>
#include <hip/hip_bf16.h>
#include <stdint.h>

// GCN on MI355X. ALL I/O IS FLOAT32 (reference is jnp.float32 end-to-end).
//   out0 = relu( (D^-1/2 A D^-1/2) @ (graph @ W) + bias )   [16,4096,64] fp32
//   out1 = adj (verbatim fp32 copy)                          [4096,4096] fp32
// Core GEMM runs bf16 MFMA (threshold 2e-2 is generous; fp32 accumulate).
// Scratch (adjb bf16 32MB + spT bf16 8MB + dsq 16KB): d_ws if big enough,
// else carved from the out1 region and overwritten by the final adj copy.

typedef __bf16 bf16;
typedef __bf16 bf16x8 __attribute__((ext_vector_type(8)));
typedef float f32x4 __attribute__((ext_vector_type(4)));

#define NN 4096
#define BATCH 16
#define FD 64

// ---------- Kernel 1: adj fp32 -> bf16 copy + rowsum -> dsq = rsqrt ----------
__global__ __launch_bounds__(256) void k_prep(const float* __restrict__ adj,
                                              bf16* __restrict__ adjb,
                                              float* __restrict__ dsq) {
    int row = blockIdx.x;
    const float4* p = (const float4*)(adj + (size_t)row * NN);  // 1024 x float4
    uint4* q = (uint4*)(adjb + (size_t)row * NN);               // 512 x (8 bf16)
    float s = 0.f;
    for (int j = threadIdx.x; j < 512; j += 256) {
        float4 a = p[2 * j], b = p[2 * j + 1];
        bf16x8 h;
        h[0] = (bf16)a.x; h[1] = (bf16)a.y; h[2] = (bf16)a.z; h[3] = (bf16)a.w;
        h[4] = (bf16)b.x; h[5] = (bf16)b.y; h[6] = (bf16)b.z; h[7] = (bf16)b.w;
        q[j] = __builtin_bit_cast(uint4, h);
        s += a.x + a.y + a.z + a.w + b.x + b.y + b.z + b.w;
    }
    #pragma unroll
    for (int off = 32; off > 0; off >>= 1) s += __shfl_down(s, off, 64);
    __shared__ float red[4];
    int lane = threadIdx.x & 63, wv = threadIdx.x >> 6;
    if (lane == 0) red[wv] = s;
    __syncthreads();
    if (threadIdx.x == 0) {
        float t = red[0] + red[1] + red[2] + red[3];
        if (t == 0.f) t = 1.f;              // isolated-node guard (ref semantics)
        dsq[row] = 1.0f / sqrtf(t);
    }
}

// ---------- Kernel 2: spT[c=b*64+o][m] = dsq[m] * sum_i graph[b,m,i]*W[i,o] ----------
__global__ __launch_bounds__(256) void k_support(const float* __restrict__ graph,
                                                 const float* __restrict__ weight,
                                                 const float* __restrict__ dsq,
                                                 bf16* __restrict__ spT) {
    __shared__ float wT[64 * 64];           // wT[o*64+i]
    int tid = threadIdx.x;
    for (int idx = tid; idx < 4096; idx += 256) {
        int i = idx >> 6, o = idx & 63;
        wT[o * 64 + i] = weight[idx];
    }
    __syncthreads();
    int b = blockIdx.y;
    int m = blockIdx.x * 256 + tid;
    const float4* g4 = (const float4*)(graph + ((size_t)b * NN + m) * FD); // 16 x float4
    float ds = dsq[m];
    float gr[64];
    #pragma unroll
    for (int j = 0; j < 16; j++) {
        float4 v = g4[j];
        gr[4 * j] = v.x * ds; gr[4 * j + 1] = v.y * ds;
        gr[4 * j + 2] = v.z * ds; gr[4 * j + 3] = v.w * ds;
    }
    bf16* outp = spT + m;
    for (int o = 0; o < 64; o++) {
        const float4* w4 = (const float4*)&wT[o * 64];
        float acc = 0.f;
        #pragma unroll
        for (int j = 0; j < 16; j++) {
            float4 wv = w4[j];
            acc += gr[4 * j] * wv.x + gr[4 * j + 1] * wv.y
                 + gr[4 * j + 2] * wv.z + gr[4 * j + 3] * wv.w;
        }
        outp[(size_t)(b * 64 + o) * NN] = (bf16)acc;
    }
}

// ---------- Kernel 3: OUT[n][c] = sum_m adjb[n][m]*spT[c][m]; fp32 epilogue ----------
// 128x128 tile, BK=32, classic VGPR->LDS staging, 16x16x32 bf16 MFMA.
__global__ __launch_bounds__(256) void k_gemm(const bf16* __restrict__ adjb,
                                              const bf16* __restrict__ spT,
                                              const float* __restrict__ dsq,
                                              const float* __restrict__ bias,
                                              float* __restrict__ out) {
    __shared__ uint4 lds_a[512];   // A tile: 128 rows x 32 k; chunk q=row*4+sub
    __shared__ uint4 lds_b[512];   // B tile: 128 c-rows x 32 k
    const int tid = threadIdx.x;
    const int lane = tid & 63;
    const int w = tid >> 6;
    const int n0 = blockIdx.x * 128;
    const int c0 = blockIdx.y * 128;

    const int q0 = tid, q1 = tid + 256;
    const uint4* pA0 = (const uint4*)(adjb + (size_t)(n0 + (q0 >> 2)) * NN) + (q0 & 3);
    const uint4* pA1 = (const uint4*)(adjb + (size_t)(n0 + (q1 >> 2)) * NN) + (q1 & 3);
    const uint4* pB0 = (const uint4*)(spT  + (size_t)(c0 + (q0 >> 2)) * NN) + (q0 & 3);
    const uint4* pB1 = (const uint4*)(spT  + (size_t)(c0 + (q1 >> 2)) * NN) + (q1 & 3);

    const int r = lane & 15, qo = lane >> 4;
    const int rm = (w >> 1) * 64, rc = (w & 1) * 64;   // 64x64 sub-tile per wave
    const bf16x8* fA = (const bf16x8*)lds_a + (rm + r) * 4 + qo;
    const bf16x8* fB = (const bf16x8*)lds_b + (rc + r) * 4 + qo;

    f32x4 acc[4][4];
    #pragma unroll
    for (int i = 0; i < 4; i++)
        #pragma unroll
        for (int j = 0; j < 4; j++)
            acc[i][j] = (f32x4){0.f, 0.f, 0.f, 0.f};

    for (int kt = 0; kt < NN; kt += 32) {
        const int kd = kt >> 3;             // uint4 step (8 bf16 per uint4)
        uint4 va0 = pA0[kd], va1 = pA1[kd];
        uint4 vb0 = pB0[kd], vb1 = pB1[kd];
        __syncthreads();                    // prior iter's reads done
        lds_a[q0] = va0; lds_a[q1] = va1;
        lds_b[q0] = vb0; lds_b[q1] = vb1;
        __syncthreads();                    // tile visible
        bf16x8 af[4], bfr[4];
        #pragma unroll
        for (int mi = 0; mi < 4; mi++) af[mi] = fA[mi * 64];
        #pragma unroll
        for (int ni = 0; ni < 4; ni++) bfr[ni] = fB[ni * 64];
        #pragma unroll
        for (int mi = 0; mi < 4; mi++)
            #pragma unroll
            for (int ni = 0; ni < 4; ni++)
                acc[mi][ni] = __builtin_amdgcn_mfma_f32_16x16x32_bf16(
                    af[mi], bfr[ni], acc[mi][ni], 0, 0, 0);
    }

    // Epilogue: relu(dsq[n]*acc + bias[o]) -> out[b, n, o];  c = c0+rc+ni*16+r
    const int b_hi = (c0 + rc) >> 6;                 // wave-uniform batch index
    float* outp = out + (size_t)b_hi * (NN * FD);
    float bo[4];
    #pragma unroll
    for (int ni = 0; ni < 4; ni++) bo[ni] = bias[ni * 16 + r];
    #pragma unroll
    for (int mi = 0; mi < 4; mi++) {
        float dn[4];
        #pragma unroll
        for (int rr = 0; rr < 4; rr++) dn[rr] = dsq[n0 + rm + mi * 16 + qo * 4 + rr];
        #pragma unroll
        for (int ni = 0; ni < 4; ni++) {
            int o = ni * 16 + r;
            #pragma unroll
            for (int rr = 0; rr < 4; rr++) {
                int n = n0 + rm + mi * 16 + qo * 4 + rr;
                float v = fmaxf(dn[rr] * acc[mi][ni][rr] + bo[ni], 0.f);
                outp[(size_t)n * FD + o] = v;
            }
        }
    }
}

// ---------- Kernel 4: adj -> out1 fp32 copy (runs LAST, overwrites scratch) ----------
__global__ __launch_bounds__(256) void k_copy(const float4* __restrict__ src,
                                              float4* __restrict__ dst) {
    size_t i = (size_t)blockIdx.x * 256 + threadIdx.x;
    dst[i] = src[i];
}

extern "C" void kernel_launch(void* const* d_in, const int* in_sizes, int n_in,
                              void* d_out, int out_size, void* d_ws, size_t ws_size,
                              hipStream_t stream) {
    // Identify inputs by element count (all distinct) — robust to ordering.
    const float *graph = nullptr, *adj = nullptr, *weight = nullptr, *bias = nullptr;
    for (int i = 0; i < n_in; i++) {
        const float* p = (const float*)d_in[i];
        switch (in_sizes[i]) {
            case BATCH * NN * FD: graph  = p; break;   // 4,194,304
            case NN * NN:         adj    = p; break;   // 16,777,216
            case FD * FD:         weight = p; break;   // 4,096
            case FD:              bias   = p; break;   // 64
        }
    }

    float* out0 = (float*)d_out;                       // [16,4096,64] fp32
    float* out1 = out0 + (size_t)BATCH * NN * FD;      // [4096,4096] fp32 (64 MB)

    // Scratch: adjb 32MB + spT 8MB + dsq 16KB. Prefer d_ws; else out1 region.
    const size_t off_spT = (size_t)NN * NN * 2;                 // after adjb
    const size_t off_dsq = off_spT + (size_t)1024 * NN * 2;     // after spT
    const size_t need    = off_dsq + (size_t)NN * 4;
    char* scratch = (ws_size >= need) ? (char*)d_ws : (char*)out1;
    bf16*  adjb = (bf16*)scratch;
    bf16*  spT  = (bf16*)(scratch + off_spT);
    float* dsq  = (float*)(scratch + off_dsq);

    hipLaunchKernelGGL(k_prep, dim3(NN), dim3(256), 0, stream, adj, adjb, dsq);
    hipLaunchKernelGGL(k_support, dim3(16, 16), dim3(256), 0, stream,
                       graph, weight, dsq, spT);
    hipLaunchKernelGGL(k_gemm, dim3(32, 8), dim3(256), 0, stream,
                       adjb, spT, dsq, bias, out0);
    hipLaunchKernelGGL(k_copy, dim3(16384), dim3(256), 0, stream,
                       (const float4*)adj, (float4*)out1);   // 4,194,304 float4
}